// Round 11
// baseline (428.505 us; speedup 1.0000x reference)
//
#include <hip/hip_runtime.h>
#include <math.h>

#define TPB 64   // ONE WAVE PER SAMPLE — no __syncthreads anywhere

// ---- LDS (floats), per-sample, lifetime-overlaid ----
// x   [0,784)       [28][28], alive until dyn
// c1  [784,1840)    conv7 out [8][11][12] (dead after conv5)
// y   [784,2474)    dyn out [10][13][13] (over c1)
// k   [2474,2514)   dynamic kernels
// f   [2514,2604)   conv5 out (dead after fc90)
// h   [2604,2636)   fc90 out (dead after fc40)
// p3  [0,320) pf [320,420) a1 [420,470) z [470,480)  (over dead x)
#define OX   0
#define OC1  784
#define OY   784
#define OK2  2474
#define OF   2514
#define OH   2604
#define OP3  0
#define OPF  320
#define OA1  420
#define OZ   470
#define SM_TOT 2636   // 10544 B -> 15 blocks/CU = 15 waves

// Intra-wave LDS ops are processed in program order (no barriers needed) —
// validated by the barrier-free tails of R7-R10. With 64-thread blocks the
// VGPR budget is ~128 (4 waves/SIMD), so the b64 stage bodies from R9/R10
// (which blew the 64-VGPR cap at 256 threads) are safe here.
__global__ __launch_bounds__(TPB) void fused_forward(
    const float* __restrict__ x,
    const float* __restrict__ kf_w1, const float* __restrict__ kf_b1,
    const float* __restrict__ kf_w2, const float* __restrict__ kf_b2,
    const float* __restrict__ kf_fc1_w, const float* __restrict__ kf_fc1_b,
    const float* __restrict__ kf_fc2_w, const float* __restrict__ kf_fc2_b,
    const float* __restrict__ conv2_w, const float* __restrict__ conv2_b,
    const float* __restrict__ fc1_w, const float* __restrict__ fc1_b,
    const float* __restrict__ fc2_w, const float* __restrict__ fc2_b,
    float* __restrict__ out)
{
    __shared__ float sm[SM_TOT];
    const int tid = threadIdx.x;
    const int n = blockIdx.x;

    // ---- stage x into LDS ----
    {
        const float4* xg = (const float4*)(x + (long long)n * 784);
        float4* d = (float4*)&sm[OX];
        for (int i = tid; i < 196; i += TPB) d[i] = xg[i];
    }

    // ---- conv7 (28->22) + pool (->11) + relu : 176 units, 3 passes ----
    // unit = (oc=u&7, py, h); cc0 = 12h (b64-aligned); h1 keeps j<5.
    for (int u = tid; u < 176; u += TPB) {
        int oc = u & 7;
        int r  = u >> 3;
        int py = r >> 1;
        int h  = r & 1;
        int cc0 = 12 * h;
        float c[2][12];
        #pragma unroll
        for (int r2 = 0; r2 < 2; ++r2)
            #pragma unroll
            for (int i = 0; i < 12; ++i) c[r2][i] = 0.f;
        float wc[7], wp[7];
        const float* wg = kf_w1 + oc * 49;
        #pragma unroll
        for (int i = 0; i < 7; ++i) wc[i] = wg[i];
        #pragma unroll
        for (int t = 0; t < 8; ++t) {
            const float2* xs = (const float2*)&sm[OX + (2 * py + t) * 28 + cc0];
            float row[18];
            #pragma unroll
            for (int p = 0; p < 9; ++p) {
                float2 v = xs[p];
                row[2 * p] = v.x; row[2 * p + 1] = v.y;
            }
            if (t <= 6) {
                #pragma unroll
                for (int kx = 0; kx < 7; ++kx)
                    #pragma unroll
                    for (int cc = 0; cc < 12; ++cc)
                        c[0][cc] = fmaf(wc[kx], row[cc + kx], c[0][cc]);
            }
            if (t >= 1) {
                #pragma unroll
                for (int kx = 0; kx < 7; ++kx)
                    #pragma unroll
                    for (int cc = 0; cc < 12; ++cc)
                        c[1][cc] = fmaf(wp[kx], row[cc + kx], c[1][cc]);
            }
            #pragma unroll
            for (int i = 0; i < 7; ++i) wp[i] = wc[i];
            if (t < 7) {
                const float* wn = wg + (t + 1) * 7;
                #pragma unroll
                for (int i = 0; i < 7; ++i) wc[i] = wn[i];
            }
        }
        float b = kf_b1[oc];
        #pragma unroll
        for (int j = 0; j < 6; ++j) {
            if (h == 0 || j < 5) {
                float m = fmaxf(fmaxf(c[0][2 * j], c[0][2 * j + 1]),
                                fmaxf(c[1][2 * j], c[1][2 * j + 1]));
                sm[OC1 + oc * 132 + py * 12 + 6 * h + j] = fmaxf(m + b, 0.f);
            }
        }
    }

    // ---- conv5 (11->7 used 6x6) + pool (->3) + relu : 90 units, 2 passes ----
    for (int u = tid; u < 90; u += TPB) {
        int oc = u % 10, r = u / 10;
        int py = r / 3, px = r % 3;
        float a00 = 0.f, a01 = 0.f, a10 = 0.f, a11 = 0.f;
        for (int ic = 0; ic < 8; ++ic) {
            float w[25];
            const float* wg = kf_w2 + (oc * 8 + ic) * 25;
            #pragma unroll
            for (int i = 0; i < 25; ++i) w[i] = wg[i];
            const float* xb = &sm[OC1 + ic * 132 + (2 * py) * 12 + 2 * px];
            float cur[6], nxt[6];
            #pragma unroll
            for (int p = 0; p < 3; ++p) {
                float2 v = ((const float2*)xb)[p];
                cur[2 * p] = v.x; cur[2 * p + 1] = v.y;
            }
            #pragma unroll
            for (int ky = 0; ky < 5; ++ky) {
                const float2* xr = (const float2*)(xb + (ky + 1) * 12);
                #pragma unroll
                for (int p = 0; p < 3; ++p) {
                    float2 v = xr[p];
                    nxt[2 * p] = v.x; nxt[2 * p + 1] = v.y;
                }
                #pragma unroll
                for (int kx = 0; kx < 5; ++kx) {
                    float wv = w[ky * 5 + kx];
                    a00 = fmaf(wv, cur[kx],     a00);
                    a01 = fmaf(wv, cur[kx + 1], a01);
                    a10 = fmaf(wv, nxt[kx],     a10);
                    a11 = fmaf(wv, nxt[kx + 1], a11);
                }
                #pragma unroll
                for (int i = 0; i < 6; ++i) cur[i] = nxt[i];
            }
        }
        float m = fmaxf(fmaxf(a00, a01), fmaxf(a10, a11)) + kf_b2[oc];
        sm[OF + oc * 9 + py * 3 + px] = fmaxf(m, 0.f);
    }

    // ---- fc 90->32 + relu : k-split over lane halves + shfl reduce ----
    {
        int o = tid & 31, g = tid >> 5;
        float acc = 0.f;
        const float* wr = &kf_fc1_w[o * 90 + g * 45];
        const float* ff = &sm[OF + g * 45];
        for (int i = 0; i < 45; ++i) acc = fmaf(wr[i], ff[i], acc);
        float other = __shfl_down(acc, 32);
        if (tid < 32) sm[OH + o] = fmaxf(kf_fc1_b[o] + acc + other, 0.f);
    }

    // ---- fc 32->40 (dynamic kernels) ----
    if (tid < 40) {
        float acc = kf_fc2_b[tid];
        const float* wr = &kf_fc2_w[tid * 32];
        #pragma unroll
        for (int i = 0; i < 32; ++i) acc = fmaf(wr[i], sm[OH + i], acc);
        sm[OK2 + tid] = acc;
    }

    // ---- dynamic 2x2 conv + pool + relu -> y [10][13][13] : 130 units ----
    for (int u = tid; u < 130; u += TPB) {
        int oc = u % 10, py = u / 10;
        float k0 = sm[OK2 + oc * 4 + 0], k1 = sm[OK2 + oc * 4 + 1];
        float k2 = sm[OK2 + oc * 4 + 2], k3 = sm[OK2 + oc * 4 + 3];
        const float* x0 = &sm[OX + 2 * py * 28];
        const float* x1 = x0 + 28;
        const float* x2 = x0 + 56;
        float A0 = x0[0], A1 = x1[0], A2 = x2[0];
        float B0 = x0[1], B1 = x1[1], B2 = x2[1];
        #pragma unroll
        for (int j = 0; j < 13; ++j) {
            float C0 = x0[2 * j + 2], C1 = x1[2 * j + 2], C2 = x2[2 * j + 2];
            float c00 = A0 * k0 + B0 * k1 + A1 * k2 + B1 * k3;
            float c01 = B0 * k0 + C0 * k1 + B1 * k2 + C1 * k3;
            float c10 = A1 * k0 + B1 * k1 + A2 * k2 + B2 * k3;
            float c11 = B1 * k0 + C1 * k1 + B2 * k2 + C2 * k3;
            float m = fmaxf(fmaxf(c00, c01), fmaxf(c10, c11));
            sm[OY + oc * 169 + py * 13 + j] = fmaxf(m, 0.f);
            A0 = C0; A1 = C1; A2 = C2;
            if (j < 12) { B0 = x0[2 * j + 3]; B1 = x1[2 * j + 3]; B2 = x2[2 * j + 3]; }
        }
    }

    // ---- conv2 5x5 (8x8 used): lane = pixel (rr,cc); acc[20] in regs;
    // weights are wave-UNIFORM -> scalar loads; pool via shfl_xor ----
    {
        int rr = tid >> 3, cc = tid & 7;
        float acc[20];
        #pragma unroll
        for (int o = 0; o < 20; ++o) acc[o] = 0.f;
        for (int ic = 0; ic < 10; ++ic) {
            float win[25];
            const float* yb = &sm[OY + ic * 169 + rr * 13 + cc];
            #pragma unroll
            for (int a = 0; a < 5; ++a)
                #pragma unroll
                for (int b = 0; b < 5; ++b) win[a * 5 + b] = yb[a * 13 + b];
            #pragma unroll
            for (int o = 0; o < 20; ++o) {
                const float* wg = conv2_w + (o * 10 + ic) * 25;   // uniform
                #pragma unroll
                for (int t = 0; t < 25; ++t)
                    acc[o] = fmaf(wg[t], win[t], acc[o]);
            }
        }
        int py = rr >> 1, px = cc >> 1;
        #pragma unroll
        for (int o = 0; o < 20; ++o) {
            float v = acc[o];
            v = fmaxf(v, __shfl_xor(v, 1));
            v = fmaxf(v, __shfl_xor(v, 8));
            if ((tid & 9) == 0)   // rr,cc both even: quad leader
                sm[OP3 + o * 16 + py * 4 + px] = fmaxf(v + conv2_b[o], 0.f);
        }
    }

    // ---- fc 320->50 + relu : 100 units (o,g-half), 2 passes; float4 reads
    // (p3 reads are uniform within each g-group -> LDS broadcast) ----
    for (int u = tid; u < 100; u += TPB) {
        int o = u % 50, g = u / 50;
        const float4* wr = (const float4*)(fc1_w + o * 320 + g * 160);
        const float4* pp = (const float4*)&sm[OP3 + g * 160];
        float a = 0.f;
        #pragma unroll
        for (int i = 0; i < 40; ++i) {
            float4 wv = wr[i], pv = pp[i];
            a = fmaf(wv.x, pv.x, a); a = fmaf(wv.y, pv.y, a);
            a = fmaf(wv.z, pv.z, a); a = fmaf(wv.w, pv.w, a);
        }
        sm[OPF + u] = a;
    }
    if (tid < 50)
        sm[OA1 + tid] = fmaxf(fc1_b[tid] + sm[OPF + tid] + sm[OPF + 50 + tid], 0.f);

    // ---- fc 50->10 ----
    if (tid < 10) {
        float a = fc2_b[tid];
        const float* wr = &fc2_w[tid * 50];
        #pragma unroll
        for (int i = 0; i < 50; ++i) a = fmaf(wr[i], sm[OA1 + i], a);
        sm[OZ + tid] = a;
    }

    // ---- log_softmax + store ----
    if (tid < 10) {
        float m = sm[OZ + 0];
        #pragma unroll
        for (int i = 1; i < 10; ++i) m = fmaxf(m, sm[OZ + i]);
        float s = 0.f;
        #pragma unroll
        for (int i = 0; i < 10; ++i) s += expf(sm[OZ + i] - m);
        out[n * 10 + tid] = sm[OZ + tid] - m - logf(s);
    }
}

extern "C" void kernel_launch(void* const* d_in, const int* in_sizes, int n_in,
                              void* d_out, int out_size, void* d_ws, size_t ws_size,
                              hipStream_t stream) {
    const float* x        = (const float*)d_in[0];
    const float* kf_w1    = (const float*)d_in[1];
    const float* kf_b1    = (const float*)d_in[2];
    const float* kf_w2    = (const float*)d_in[3];
    const float* kf_b2    = (const float*)d_in[4];
    const float* kf_fc1_w = (const float*)d_in[5];
    const float* kf_fc1_b = (const float*)d_in[6];
    const float* kf_fc2_w = (const float*)d_in[7];
    const float* kf_fc2_b = (const float*)d_in[8];
    const float* conv2_w  = (const float*)d_in[9];
    const float* conv2_b  = (const float*)d_in[10];
    const float* fc1_w    = (const float*)d_in[11];
    const float* fc1_b    = (const float*)d_in[12];
    const float* fc2_w    = (const float*)d_in[13];
    const float* fc2_b    = (const float*)d_in[14];

    const int N = in_sizes[0] / 784;   // 8192

    fused_forward<<<N, TPB, 0, stream>>>(
        x, kf_w1, kf_b1, kf_w2, kf_b2, kf_fc1_w, kf_fc1_b, kf_fc2_w, kf_fc2_b,
        conv2_w, conv2_b, fc1_w, fc1_b, fc2_w, fc2_b, (float*)d_out);
}